// Round 4
// baseline (132.966 us; speedup 1.0000x reference)
//
#include <hip/hip_runtime.h>

namespace {
constexpr int N_ = 16, C_ = 112, H_ = 48, W_ = 48, HW_ = 2304;
// ws float offsets
constexpr int WS_T7 = 0;         // N*H = 768
constexpr int WS_T17 = 768;      // N*7 = 112
constexpr int WS_A = 1024;       // N*C = 1792
constexpr int WS_V = 4096;       // N*C*7 = 12544
constexpr int WS_G = 16896;      // N*C*C = 200704
constexpr int WS_SPART = 217600; // nch*N*C*C
}

__device__ __forceinline__ float f4e(const float4& v, int e) {
  return e == 0 ? v.x : e == 1 ? v.y : e == 2 ? v.z : v.w;
}

// ---------------------------------------------------------------------------
// K1: channel-mean rows -> t7. t7 value from mean-row h' lands at (h'+2)%48.
// grid (16, N), 192 threads, 3 h-rows per block
__global__ __launch_bounds__(192) void ath_stats(const float* __restrict__ x,
                                                 const float* __restrict__ p7,
                                                 float* __restrict__ ws) {
  const int hg = blockIdx.x;
  const int n = blockIdx.y;
  const int tid = threadIdx.x;
  __shared__ float mxs[144];
  if (tid < 144) {
    const float* xb = x + (size_t)n * C_ * HW_ + hg * 144 + tid;
    float a0 = 0.f, a1 = 0.f, a2 = 0.f, a3 = 0.f;
    for (int c = 0; c < C_; c += 4) {
      a0 += xb[(size_t)c * HW_];
      a1 += xb[(size_t)(c + 1) * HW_];
      a2 += xb[(size_t)(c + 2) * HW_];
      a3 += xb[(size_t)(c + 3) * HW_];
    }
    mxs[tid] = (a0 + a1 + a2 + a3) * (1.0f / 112.0f);
  }
  __syncthreads();
  if (tid < 3) {
    float s = 0.f;
    for (int k = 0; k < 3; ++k)
      for (int wp = 0; wp < W_; ++wp) {
        int j = 3 * k + wp - 3;
        if (j >= 0 && j < W_) s += mxs[tid * 48 + j] * p7[k * W_ + wp];
      }
    const int hsrc = hg * 3 + tid;
    ws[WS_T7 + n * H_ + (hsrc + 2) % 48] = s;  // S3=+1,S6=+1 -> +2 shift
  }
}

// ---------------------------------------------------------------------------
// K2: t17[n,kk] = (1/48) sum_h |t7pad[n, 2kk+h-6]| ; grid N, 64 threads
__global__ __launch_bounds__(64) void ath_t17(float* __restrict__ ws) {
  const int n = blockIdx.x;
  const int tid = threadIdx.x;
  __shared__ float t7s[48];
  if (tid < 48) t7s[tid] = ws[WS_T7 + n * H_ + tid];
  __syncthreads();
  if (tid < 7) {
    float s = 0.f;
    for (int hh = 0; hh < 48; ++hh) {
      int j = 2 * tid + hh - 6;
      if (j >= 0 && j < 48) s += fabsf(t7s[j]);
    }
    ws[WS_T17 + n * 7 + tid] = s * (1.0f / 48.0f);
  }
}

// ---------------------------------------------------------------------------
// K3: per (n,c): V[n,c,m] (mod-7 bucket sums), A'[n,c]. grid (C,N), 64 thr
__global__ __launch_bounds__(64) void ath_colstats(const float* __restrict__ x,
                                                   const float* __restrict__ p19,
                                                   float* __restrict__ ws) {
  const int c = blockIdx.x, n = blockIdx.y;
  const int tid = threadIdx.x;
  const float* xb = x + ((size_t)n * C_ + c) * HW_;
  float rowsum = 0.f;
  if (tid < 48) {
    const float4* xr = (const float4*)(xb + tid * W_);
#pragma unroll
    for (int q = 0; q < 12; ++q) {
      float4 v = xr[q];
      rowsum += v.x + v.y + v.z + v.w;
    }
  }
  float vb[7] = {0.f, 0.f, 0.f, 0.f, 0.f, 0.f, 0.f};
#pragma unroll
  for (int jj = 0; jj < 9; ++jj) {
    int p0 = (tid + 64 * jj) * 4;
    float4 v = *(const float4*)&xb[p0];
    int h = p0 / 48;
    int w = p0 - h * 48;
    int m0 = (w - h + 49) % 7;
#pragma unroll
    for (int r = 0; r < 4; ++r) {
      int mr = m0 + r;
      mr = (mr >= 7) ? mr - 7 : mr;
      float val = f4e(v, r);
#pragma unroll
      for (int j = 0; j < 7; ++j) vb[j] += (mr == j) ? val : 0.f;
    }
  }
#pragma unroll
  for (int j = 0; j < 7; ++j) {
#pragma unroll
    for (int off = 32; off >= 1; off >>= 1) vb[j] += __shfl_xor(vb[j], off);
  }
  if (tid == 0) {
#pragma unroll
    for (int j = 0; j < 7; ++j) ws[WS_V + ((size_t)n * C_ + c) * 7 + j] = vb[j];
  }
  // A'[n,c] = (2/48)*p19[c]*sum_h t7[h]*(rowsum[h] + D[(c-h)%7]), D[s]=7T - t17[(s+6)%7]
  const float* t7p = ws + WS_T7 + n * H_;
  const float* t17p = ws + WS_T17 + n * 7;
  float T = 0.f;
#pragma unroll
  for (int j = 0; j < 7; ++j) T += t17p[j];
  float term = 0.f;
  if (tid < 48) {
    int idx6 = ((c - tid + 6) % 7 + 7) % 7;
    float D = 7.f * T - t17p[idx6];
    term = t7p[tid] * (rowsum + D);
  }
#pragma unroll
  for (int off = 32; off >= 1; off >>= 1) term += __shfl_xor(term, off);
  if (tid == 0) ws[WS_A + n * C_ + c] = p19[c] * term * (2.0f / 48.0f);
}

// ---------------------------------------------------------------------------
// K4: Gram partials. grid N*nch, 256 threads, 8x8 tile on c-padded-128 slab,
// 48-row LDS passes.
__global__ __launch_bounds__(256) void ath_gram(const float* __restrict__ x,
                                                float* __restrict__ ws,
                                                int nch, int KC) {
  const int bid = blockIdx.x;
  const int n = bid / nch;
  const int kc = bid - n * nch;
  const int p0 = kc * KC;
  const int tid = threadIdx.x;
  __shared__ float xs[48][132];
  // zero the c-pad (cols 112..127) once
  for (int idx = tid; idx < 48 * 16; idx += 256) {
    int k = idx / 16, cc = 112 + (idx % 16);
    xs[k][cc] = 0.f;
  }
  float acc[8][8];
#pragma unroll
  for (int a = 0; a < 8; ++a)
#pragma unroll
    for (int b = 0; b < 8; ++b) acc[a][b] = 0.f;
  const int tc = tid >> 4, ti = tid & 15;
  const int c0 = tc * 8, i0 = ti * 8;
  const float* xb = x + (size_t)n * C_ * HW_;
  for (int ks = 0; ks < KC; ks += 48) {
    __syncthreads();
    for (int idx = tid; idx < C_ * 48; idx += 256) {
      int cc = idx / 48, k = idx - cc * 48;
      xs[k][cc] = xb[(size_t)cc * HW_ + p0 + ks + k];
    }
    __syncthreads();
#pragma unroll 2
    for (int k = 0; k < 48; ++k) {
      float4 a0 = *(const float4*)&xs[k][c0];
      float4 a1 = *(const float4*)&xs[k][c0 + 4];
      float4 b0 = *(const float4*)&xs[k][i0];
      float4 b1 = *(const float4*)&xs[k][i0 + 4];
      float av[8] = {a0.x, a0.y, a0.z, a0.w, a1.x, a1.y, a1.z, a1.w};
      float bv[8] = {b0.x, b0.y, b0.z, b0.w, b1.x, b1.y, b1.z, b1.w};
#pragma unroll
      for (int r = 0; r < 8; ++r)
#pragma unroll
        for (int q = 0; q < 8; ++q) acc[r][q] += av[r] * bv[q];
    }
  }
  if (c0 < 112 && i0 < 112) {
    float* sp = ws + WS_SPART + (size_t)bid * (C_ * C_);
#pragma unroll
    for (int r = 0; r < 8; ++r) {
      *(float4*)&sp[(c0 + r) * C_ + i0] =
          make_float4(acc[r][0], acc[r][1], acc[r][2], acc[r][3]);
      *(float4*)&sp[(c0 + r) * C_ + i0 + 4] =
          make_float4(acc[r][4], acc[r][5], acc[r][6], acc[r][7]);
    }
  }
}

// ---------------------------------------------------------------------------
// K5: G'[n,c,i] = p19[c]*(S + sum_m t17[(c+m)%7]*V[n,i,m]) / (48*sqrt(112))
// float4 over i. grid 196 x 256
__global__ __launch_bounds__(256) void ath_assemble(const float* __restrict__ p19,
                                                    float* __restrict__ ws,
                                                    int nch) {
  const int idx4 = blockIdx.x * 256 + threadIdx.x;
  if (idx4 >= N_ * C_ * C_ / 4) return;
  const int n = idx4 / 3136;
  const int r4 = idx4 - n * 3136;
  const int c = (r4 * 4) / C_;
  const int i0 = (r4 * 4) - c * C_;
  float4 s = make_float4(0.f, 0.f, 0.f, 0.f);
  for (int kc = 0; kc < nch; ++kc) {
    float4 v = *(const float4*)&ws[WS_SPART + (size_t)(n * nch + kc) * (C_ * C_) + r4 * 4];
    s.x += v.x; s.y += v.y; s.z += v.z; s.w += v.w;
  }
  const float* t17p = ws + WS_T17 + n * 7;
  const float scale = 1.0f / (48.0f * sqrtf(112.0f));
  const float pc = p19[c];
  float o[4];
#pragma unroll
  for (int e = 0; e < 4; ++e) {
    const float* vp = ws + WS_V + ((size_t)n * C_ + i0 + e) * 7;
    float t = 0.f;
    int j0 = c % 7;
#pragma unroll
    for (int m = 0; m < 7; ++m) {
      int jj = j0 + m;
      jj = (jj >= 7) ? jj - 7 : jj;
      t += t17p[jj] * vp[m];
    }
    o[e] = pc * (f4e(s, e) + t) * scale;
  }
  *(float4*)&ws[WS_G + idx4 * 4] = make_float4(o[0], o[1], o[2], o[3]);
}

// ---------------------------------------------------------------------------
// K6 fused conv + GEMM, software-pipelined, t13 in-place in xs.
// xs[c][52]: x at cols 2..49 (zeros at 0,1,50,51); t13 overwrites cols 0..47.
__device__ __forceinline__ void load_u(float4 (&u)[8], const float (*xs)[52],
                                       int ii, int w0) {
#pragma unroll
  for (int r = 0; r < 4; ++r) {
    u[2 * r] = *(const float4*)&xs[ii + r][w0];
    u[2 * r + 1] = *(const float4*)&xs[ii + r][w0 + 4];
  }
}
__device__ __forceinline__ void load_w(float4 (&wv)[3], const float* __restrict__ cw,
                                       int o, int g) {
  const float4* p = (const float4*)(cw + ((size_t)o * C_ + 4 * g) * 3);
  wv[0] = p[0]; wv[1] = p[1]; wv[2] = p[2];
}
__device__ __forceinline__ void conv_fma(float (&accj)[4], const float4 (&u)[8],
                                         const float4 (&wv)[3]) {
#pragma unroll
  for (int r = 0; r < 4; ++r)
#pragma unroll
    for (int kx = 0; kx < 3; ++kx) {
      const int wi = 3 * r + kx;
      float w = f4e(wv[wi >> 2], wi & 3);
#pragma unroll
      for (int l = 0; l < 4; ++l) {
        const int t = l + 2 * kx;
        accj[l] += w * f4e(u[2 * r + (t >> 2)], t & 3);
      }
    }
}
__device__ __forceinline__ void load_s(float4 (&s)[4], const float (*xs)[52],
                                       int g, int w0) {
#pragma unroll
  for (int r = 0; r < 4; ++r) s[r] = *(const float4*)&xs[4 * g + r][w0];
}
__device__ __forceinline__ void load_g(float4 (&gv)[7], const float* __restrict__ gp,
                                       int o0, int g) {
#pragma unroll
  for (int j = 0; j < 7; ++j)
    gv[j] = *(const float4*)&gp[(size_t)(o0 + j) * C_ + 4 * g];
}
__device__ __forceinline__ void gemm_fma(float (&acc)[7][4], const float4 (&s)[4],
                                         const float4 (&gv)[7]) {
#pragma unroll
  for (int j = 0; j < 7; ++j)
#pragma unroll
    for (int r = 0; r < 4; ++r) {
      float g = f4e(gv[j], r);
#pragma unroll
      for (int l = 0; l < 4; ++l) acc[j][l] += g * f4e(s[r], l);
    }
}

__global__ __launch_bounds__(256, 3) void ath_fused(const float* __restrict__ x,
                                                    const float* __restrict__ cw,
                                                    const float* __restrict__ ws,
                                                    float* __restrict__ out) {
  const int h = blockIdx.x, n = blockIdx.y;
  const int tid = threadIdx.x;
  __shared__ float xs[C_][52];
  const float* xb = x + (size_t)n * C_ * HW_ + h * W_;
  // stage interior via float4 (dest cols 4q+2..4q+5, written as two b64s)
  for (int idx = tid; idx < C_ * 12; idx += 256) {
    int i = idx / 12, q = idx - i * 12;
    float4 v = *(const float4*)&xb[(size_t)i * HW_ + 4 * q];
    *(float2*)&xs[i][4 * q + 2] = float2{v.x, v.y};
    *(float2*)&xs[i][4 * q + 4] = float2{v.z, v.w};
  }
  // edges: cols 0,1,50,51 = 0
  for (int idx = tid; idx < C_ * 4; idx += 256) {
    int i = idx / 4, e = idx - i * 4;
    int col = (e < 2) ? e : 48 + e;
    xs[i][col] = 0.f;
  }
  __syncthreads();
  const int og = tid / 12, wq = tid - og * 12;
  const int o0 = og * 7, w0 = wq * 4;
  float4 t13v[7];
  if (tid < 192) {
    float acc[7][4];
#pragma unroll
    for (int j = 0; j < 7; ++j)
#pragma unroll
      for (int l = 0; l < 4; ++l) acc[j][l] = 0.f;
    float4 uA[8], uB[8], wA[3], wB[3];
    load_u(uA, xs, 0, w0);
    load_w(wA, cw, o0 + 0, 0);
    for (int g = 0; g < 28; g += 2) {
      load_u(uB, xs, 4 * (g + 1), w0);
      load_w(wB, cw, o0 + 1, g);     conv_fma(acc[0], uA, wA);
      load_w(wA, cw, o0 + 2, g);     conv_fma(acc[1], uA, wB);
      load_w(wB, cw, o0 + 3, g);     conv_fma(acc[2], uA, wA);
      load_w(wA, cw, o0 + 4, g);     conv_fma(acc[3], uA, wB);
      load_w(wB, cw, o0 + 5, g);     conv_fma(acc[4], uA, wA);
      load_w(wA, cw, o0 + 6, g);     conv_fma(acc[5], uA, wB);
      load_w(wB, cw, o0 + 0, g + 1); conv_fma(acc[6], uA, wA);
      const int gn = (g + 2 < 28) ? (g + 2) : 0;
      load_u(uA, xs, 4 * gn, w0);
      load_w(wA, cw, o0 + 1, g + 1); conv_fma(acc[0], uB, wB);
      load_w(wB, cw, o0 + 2, g + 1); conv_fma(acc[1], uB, wA);
      load_w(wA, cw, o0 + 3, g + 1); conv_fma(acc[2], uB, wB);
      load_w(wB, cw, o0 + 4, g + 1); conv_fma(acc[3], uB, wA);
      load_w(wA, cw, o0 + 5, g + 1); conv_fma(acc[4], uB, wB);
      load_w(wB, cw, o0 + 6, g + 1); conv_fma(acc[5], uB, wA);
      load_w(wA, cw, o0 + 0, gn);    conv_fma(acc[6], uB, wB);
    }
    // t13 = max(-conv, x); x[w0+l] is at col w0+l+2
#pragma unroll
    for (int j = 0; j < 7; ++j) {
      float4 xa = *(const float4*)&xs[o0 + j][w0];
      float4 xb2 = *(const float4*)&xs[o0 + j][w0 + 4];
      t13v[j].x = fmaxf(-acc[j][0], xa.z);
      t13v[j].y = fmaxf(-acc[j][1], xa.w);
      t13v[j].z = fmaxf(-acc[j][2], xb2.x);
      t13v[j].w = fmaxf(-acc[j][3], xb2.y);
    }
  }
  __syncthreads();  // all conv LDS reads complete
  if (tid < 192) {
#pragma unroll
    for (int j = 0; j < 7; ++j) *(float4*)&xs[o0 + j][w0] = t13v[j];
  }
  __syncthreads();  // t13 visible
  if (tid < 192) {
    const float* gp = ws + WS_G + (size_t)n * C_ * C_;
    float acc2[7][4];
#pragma unroll
    for (int j = 0; j < 7; ++j)
#pragma unroll
      for (int l = 0; l < 4; ++l) acc2[j][l] = 0.f;
    float4 sA[4], sB[4], gA[7], gB[7];
    load_s(sA, xs, 0, w0);
    load_g(gA, gp, o0, 0);
    for (int g = 0; g < 28; g += 2) {
      load_s(sB, xs, g + 1, w0);
      load_g(gB, gp, o0, g + 1);
      gemm_fma(acc2, sA, gA);
      const int gn = (g + 2 < 28) ? (g + 2) : 0;
      load_s(sA, xs, gn, w0);
      load_g(gA, gp, o0, gn);
      gemm_fma(acc2, sB, gB);
    }
#pragma unroll
    for (int j = 0; j < 7; ++j) {
      float ap = ws[WS_A + n * C_ + o0 + j];
      float4 o;
      o.x = ap - acc2[j][0];
      o.y = ap - acc2[j][1];
      o.z = ap - acc2[j][2];
      o.w = ap - acc2[j][3];
      *(float4*)&out[((size_t)n * C_ + o0 + j) * HW_ + h * W_ + w0] = o;
    }
  }
}

// ---------------------------------------------------------------------------
extern "C" void kernel_launch(void* const* d_in, const int* in_sizes, int n_in,
                              void* d_out, int out_size, void* d_ws, size_t ws_size,
                              hipStream_t stream) {
  const float* x = (const float*)d_in[0];
  const float* p7 = (const float*)d_in[1];
  // d_in[2] (p8_w) cancels algebraically: t10 = t8 - (x + t8) = -x
  const float* p19 = (const float*)d_in[3];
  const float* cw = (const float*)d_in[4];
  float* ws = (float*)d_ws;
  float* out = (float*)d_out;

  const int ladder[10] = {48, 24, 16, 12, 8, 6, 4, 3, 2, 1};
  int nch = 1;
  for (int li = 0; li < 10; ++li) {
    size_t need = ((size_t)WS_SPART + (size_t)ladder[li] * N_ * C_ * C_) * sizeof(float);
    if (need <= ws_size) { nch = ladder[li]; break; }
  }
  const int KC = HW_ / nch;

  ath_stats<<<dim3(16, N_), 192, 0, stream>>>(x, p7, ws);
  ath_t17<<<N_, 64, 0, stream>>>(ws);
  ath_colstats<<<dim3(C_, N_), 64, 0, stream>>>(x, p19, ws);
  ath_gram<<<N_ * nch, 256, 0, stream>>>(x, ws, nch, KC);
  ath_assemble<<<(N_ * C_ * C_ / 4 + 255) / 256, 256, 0, stream>>>(p19, ws, nch);
  ath_fused<<<dim3(H_, N_), 256, 0, stream>>>(x, cw, ws, out);
}